// Round 19
// baseline (388.100 us; speedup 1.0000x reference)
//
#include <hip/hip_runtime.h>
#include <math.h>

#define Sn 4
#define Bn 8
#define Ln 512
#define Dn 128
#define Hn 128
#define NOPn 64
#define Wn 2048

// ESTABLISHED: inputs fp32 insertion order; output fp32; bf16-space compare
// (thr 3.6e-2); ws = 512MB; harness tax ~170-200us/iter (input restore +
// ws poison). R18 381us. R19: fuse 6 kernels -> 3 (prep branches, up+pool+
// gates via atomics + last-block-done).

__device__ __forceinline__ float bf2f(unsigned short u) {
    return __uint_as_float(((unsigned int)u) << 16);
}
__device__ __forceinline__ unsigned short f2bf(float f) {
    unsigned int u = __float_as_uint(f);
    return (unsigned short)((u + 0x7FFFu + ((u >> 16) & 1u)) >> 16);  // RNE
}

// ---------------------------------------------------------------------------
// prep_k: blockIdx branches.
//   0..255   : dual GEMM tile (wkh/wsh from word_outputs)
//   256..263 : op-embedding GEMM tile (oph)
//   264..271 : compact pooled indices for b = bid-264
//   272      : zero gwacc (1024 f) + done counter
// ---------------------------------------------------------------------------
__global__ __launch_bounds__(256) void prep_k(const float* __restrict__ A,
                                              const float* __restrict__ W1,
                                              const float* __restrict__ W2,
                                              const float* __restrict__ b1,
                                              const float* __restrict__ b2,
                                              unsigned short* __restrict__ C1,
                                              unsigned short* __restrict__ C2,
                                              const float* __restrict__ ope,
                                              const float* __restrict__ owW,
                                              const float* __restrict__ owb,
                                              unsigned short* __restrict__ oph,
                                              const float* __restrict__ goal,
                                              const float* __restrict__ wes,
                                              int* __restrict__ widx,
                                              int* __restrict__ wcnt,
                                              float* __restrict__ gwacc,
                                              int* __restrict__ done) {
    __shared__ __align__(16) float lA[32][68];
    __shared__ __align__(16) float lW1[32][132];
    __shared__ __align__(16) float lW2[32][132];
    __shared__ int cnt;
    const int bid = blockIdx.x, tid = threadIdx.x;

    if (bid < 256) {  // ---- dual GEMM ----
        const int m0 = bid * 64;
        float acc1[4][8] = {}, acc2[4][8] = {};
        const int r0 = (tid & 15) * 4;
        const int h0 = (tid >> 4) * 8;
        for (int k0 = 0; k0 < 128; k0 += 32) {
            __syncthreads();
            {
                const int r = tid >> 2, kk = (tid & 3) * 8;
                const float* src = A + (size_t)(m0 + r) * 128 + (k0 + kk);
                float4 v0 = reinterpret_cast<const float4*>(src)[0];
                float4 v1 = reinterpret_cast<const float4*>(src)[1];
                lA[kk + 0][r] = v0.x; lA[kk + 1][r] = v0.y;
                lA[kk + 2][r] = v0.z; lA[kk + 3][r] = v0.w;
                lA[kk + 4][r] = v1.x; lA[kk + 5][r] = v1.y;
                lA[kk + 6][r] = v1.z; lA[kk + 7][r] = v1.w;
            }
            {
                const int kk = tid >> 3, hh = (tid & 7) * 16;
                const float* s1 = W1 + (size_t)(k0 + kk) * 128 + hh;
                const float* s2 = W2 + (size_t)(k0 + kk) * 128 + hh;
#pragma unroll
                for (int q = 0; q < 4; ++q) {
                    float4 v1 = reinterpret_cast<const float4*>(s1)[q];
                    float4 v2 = reinterpret_cast<const float4*>(s2)[q];
                    lW1[kk][hh + 4 * q + 0] = v1.x; lW1[kk][hh + 4 * q + 1] = v1.y;
                    lW1[kk][hh + 4 * q + 2] = v1.z; lW1[kk][hh + 4 * q + 3] = v1.w;
                    lW2[kk][hh + 4 * q + 0] = v2.x; lW2[kk][hh + 4 * q + 1] = v2.y;
                    lW2[kk][hh + 4 * q + 2] = v2.z; lW2[kk][hh + 4 * q + 3] = v2.w;
                }
            }
            __syncthreads();
#pragma unroll
            for (int k = 0; k < 32; ++k) {
                float4 a   = *reinterpret_cast<const float4*>(&lA[k][r0]);
                float4 w10 = *reinterpret_cast<const float4*>(&lW1[k][h0]);
                float4 w11 = *reinterpret_cast<const float4*>(&lW1[k][h0 + 4]);
                float4 w20 = *reinterpret_cast<const float4*>(&lW2[k][h0]);
                float4 w21 = *reinterpret_cast<const float4*>(&lW2[k][h0 + 4]);
                float av[4] = {a.x, a.y, a.z, a.w};
                float wv1[8] = {w10.x, w10.y, w10.z, w10.w, w11.x, w11.y, w11.z, w11.w};
                float wv2[8] = {w20.x, w20.y, w20.z, w20.w, w21.x, w21.y, w21.z, w21.w};
#pragma unroll
                for (int i = 0; i < 4; ++i)
#pragma unroll
                    for (int j = 0; j < 8; ++j) {
                        acc1[i][j] = fmaf(av[i], wv1[j], acc1[i][j]);
                        acc2[i][j] = fmaf(av[i], wv2[j], acc2[i][j]);
                    }
            }
        }
#pragma unroll
        for (int i = 0; i < 4; ++i) {
            alignas(16) unsigned short u1[8], u2[8];
#pragma unroll
            for (int j = 0; j < 8; ++j) {
                u1[j] = f2bf(acc1[i][j] + b1[h0 + j]);
                u2[j] = f2bf(acc2[i][j] + b2[h0 + j]);
            }
            const size_t off = (size_t)(m0 + r0 + i) * 128 + h0;
            *reinterpret_cast<uint4*>(C1 + off) = *reinterpret_cast<const uint4*>(u1);
            *reinterpret_cast<uint4*>(C2 + off) = *reinterpret_cast<const uint4*>(u2);
        }
    } else if (bid < 264) {  // ---- oph GEMM ----
        const int m0 = (bid - 256) * 64;
        float acc[4][8] = {};
        const int r0 = (tid & 15) * 4;
        const int h0 = (tid >> 4) * 8;
        for (int k0 = 0; k0 < 128; k0 += 32) {
            __syncthreads();
            {
                const int r = tid >> 2, kk = (tid & 3) * 8;
                const float* src = ope + (size_t)(m0 + r) * 128 + (k0 + kk);
                float4 v0 = reinterpret_cast<const float4*>(src)[0];
                float4 v1 = reinterpret_cast<const float4*>(src)[1];
                lA[kk + 0][r] = v0.x; lA[kk + 1][r] = v0.y;
                lA[kk + 2][r] = v0.z; lA[kk + 3][r] = v0.w;
                lA[kk + 4][r] = v1.x; lA[kk + 5][r] = v1.y;
                lA[kk + 6][r] = v1.z; lA[kk + 7][r] = v1.w;
            }
            {
                const int kk = tid >> 3, hh = (tid & 7) * 16;
                const float* src = owW + (size_t)(k0 + kk) * 128 + hh;
#pragma unroll
                for (int q = 0; q < 4; ++q) {
                    float4 v = reinterpret_cast<const float4*>(src)[q];
                    lW1[kk][hh + 4 * q + 0] = v.x; lW1[kk][hh + 4 * q + 1] = v.y;
                    lW1[kk][hh + 4 * q + 2] = v.z; lW1[kk][hh + 4 * q + 3] = v.w;
                }
            }
            __syncthreads();
#pragma unroll
            for (int k = 0; k < 32; ++k) {
                float4 a  = *reinterpret_cast<const float4*>(&lA[k][r0]);
                float4 w0 = *reinterpret_cast<const float4*>(&lW1[k][h0]);
                float4 w1 = *reinterpret_cast<const float4*>(&lW1[k][h0 + 4]);
                float av[4] = {a.x, a.y, a.z, a.w};
                float wv[8] = {w0.x, w0.y, w0.z, w0.w, w1.x, w1.y, w1.z, w1.w};
#pragma unroll
                for (int i = 0; i < 4; ++i)
#pragma unroll
                    for (int j = 0; j < 8; ++j) acc[i][j] = fmaf(av[i], wv[j], acc[i][j]);
            }
        }
#pragma unroll
        for (int i = 0; i < 4; ++i) {
            alignas(16) unsigned short us[8];
#pragma unroll
            for (int j = 0; j < 8; ++j) us[j] = f2bf(acc[i][j] + owb[h0 + j]);
            *reinterpret_cast<uint4*>(oph + (size_t)(m0 + r0 + i) * 128 + h0) =
                *reinterpret_cast<const uint4*>(us);
        }
    } else if (bid < 272) {  // ---- compact ----
        const int b = bid - 264;
        if (tid == 0) cnt = 0;
        __syncthreads();
#pragma unroll
        for (int j = 0; j < 8; ++j) {
            const int w = tid * 8 + j;
            if (goal[b * Wn + w] != 0.f && wes[b * Wn + w] != 0.f) {
                const int p = atomicAdd(&cnt, 1);
                if (p < 1024) widx[b * 1024 + p] = w;
            }
        }
        __syncthreads();
        if (tid == 0) wcnt[b] = cnt < 1024 ? cnt : 1024;
    } else {  // ---- zero accumulators ----
        for (int idx = tid; idx < 1024; idx += 256) gwacc[idx] = 0.f;
        if (tid == 0) *done = 0;
    }
}

// ---------------------------------------------------------------------------
// mega_agg: ONE block (256 thr / 4 waves) per pooled destination row.
// ---------------------------------------------------------------------------
__global__ __launch_bounds__(256) void mega_agg(const int* __restrict__ widx,
                                                const int* __restrict__ wcnt,
                                                const float* __restrict__ ww,
                                                const float* __restrict__ wem,
                                                const float* __restrict__ dep,
                                                const float* __restrict__ wop,
                                                const unsigned short* __restrict__ oph,
                                                const unsigned short* __restrict__ wkh,
                                                const unsigned short* __restrict__ wsh,
                                                unsigned short* __restrict__ nbc) {
    const int slot = blockIdx.x;          // b*1024 + i
    const int b = slot >> 10, i = slot & 1023;
    if (i >= wcnt[b]) return;             // uniform exit
    const int w_dst = widx[slot];
    const int t = threadIdx.x;
    const int lane = t & 63, wv = t >> 6;

    __shared__ int kidx[512];
    __shared__ int keep[512];
    __shared__ int sidx[256];
    __shared__ int kn, sn;
    __shared__ float part1[4][128];
    __shared__ float part2[4][128];
    if (t == 0) { kn = 0; sn = 0; }
    __syncthreads();

    const float* wwr = ww + ((size_t)(b * Wn + w_dst)) * Wn;
#pragma unroll
    for (int q = 0; q < 2; ++q) {
        const int e0 = q * 1024 + t * 4;
        float4 v = *reinterpret_cast<const float4*>(wwr + e0);
        float vv[4] = {v.x, v.y, v.z, v.w};
#pragma unroll
        for (int j = 0; j < 4; ++j)
            if (vv[j] != 0.f) {
                int p = atomicAdd(&kn, 1);
                if (p < 512) kidx[p] = e0 + j;
            }
    }
    const int sD = w_dst >> 9, lD = w_dst & 511;
    if (t < 128) {
        const float* dr = dep + ((size_t)((sD * Bn + b) * Ln + lD)) * Ln + t * 4;
        float4 v = *reinterpret_cast<const float4*>(dr);
        float vv[4] = {v.x, v.y, v.z, v.w};
#pragma unroll
        for (int j = 0; j < 4; ++j)
            if (vv[j] != 0.f) {
                int p = atomicAdd(&sn, 1);
                if (p < 256) sidx[p] = t * 4 + j;
            }
    }
    float m_op = 0.f;
    if (wv == 3) m_op = wop[((size_t)(b * Wn + w_dst)) * NOPn + lane];
    __syncthreads();

    const int nk = kn < 512 ? kn : 512;
    const int ns = sn < 256 ? sn : 256;
    for (int p = t; p < nk; p += 256)
        keep[p] = (wem[((size_t)(b * Wn + w_dst)) * Wn + kidx[p]] != 0.f) ? 1 : 0;
    __syncthreads();

    {   // slot1 gather
        float a0 = 0.f, a1 = 0.f;
        for (int p = wv; p < nk; p += 4)
            if (keep[p]) {
                const int w = kidx[p];
                const int s = w >> 9, l = w & 511;
                ushort2 x = *reinterpret_cast<const ushort2*>(
                    wkh + ((size_t)((s * Bn + b) * Ln + l)) * Hn + 2 * lane);
                a0 += bf2f(x.x);
                a1 += bf2f(x.y);
            }
        part1[wv][2 * lane]     = a0;
        part1[wv][2 * lane + 1] = a1;
    }
    {   // slot2 gather
        const unsigned short* base = wsh + (size_t)((sD * Bn + b) * Ln) * Hn + 2 * lane;
        float a0 = 0.f, a1 = 0.f;
        for (int p = wv; p < ns; p += 4) {
            ushort2 x = *reinterpret_cast<const ushort2*>(base + (size_t)sidx[p] * Hn);
            a0 += bf2f(x.x);
            a1 += bf2f(x.y);
        }
        part2[wv][2 * lane]     = a0;
        part2[wv][2 * lane + 1] = a1;
    }
    if (wv == 3) {  // slot0
        unsigned long long bal = __ballot(m_op != 0.f);
        float a0 = 0.f, a1 = 0.f;
        const unsigned short* base = oph + (size_t)b * NOPn * Hn + 2 * lane;
        while (bal) {
            const int o = __ffsll(bal) - 1;
            bal &= bal - 1;
            ushort2 v = *reinterpret_cast<const ushort2*>(base + o * Hn);
            a0 += bf2f(v.x);
            a1 += bf2f(v.y);
        }
        float ss = a0 * a0 + a1 * a1;
#pragma unroll
        for (int off = 1; off < 64; off <<= 1) ss += __shfl_xor(ss, off);
        const float sc = 1.f / (sqrtf(ss) + 1e-30f);
        ushort2 o2 = {f2bf(a0 * sc), f2bf(a1 * sc)};
        *reinterpret_cast<ushort2*>(nbc + (size_t)slot * 384 + 2 * lane) = o2;
    }
    __syncthreads();

    if (wv == 0) {
        float s0 = 0.f, s1 = 0.f;
#pragma unroll
        for (int q = 0; q < 4; ++q) {
            s0 += part1[q][2 * lane];
            s1 += part1[q][2 * lane + 1];
        }
        float ss = s0 * s0 + s1 * s1;
#pragma unroll
        for (int off = 1; off < 64; off <<= 1) ss += __shfl_xor(ss, off);
        const float sc = 1.f / (sqrtf(ss) + 1e-30f);
        ushort2 o2 = {f2bf(s0 * sc), f2bf(s1 * sc)};
        *reinterpret_cast<ushort2*>(nbc + (size_t)slot * 384 + 128 + 2 * lane) = o2;
    } else if (wv == 1) {
        float s0 = 0.f, s1 = 0.f;
#pragma unroll
        for (int q = 0; q < 4; ++q) {
            s0 += part2[q][2 * lane];
            s1 += part2[q][2 * lane + 1];
        }
        float ss = s0 * s0 + s1 * s1;
#pragma unroll
        for (int off = 1; off < 64; off <<= 1) ss += __shfl_xor(ss, off);
        const float sc = 1.f / (sqrtf(ss) + 1e-30f);
        ushort2 o2 = {f2bf(s0 * sc), f2bf(s1 * sc)};
        *reinterpret_cast<ushort2*>(nbc + (size_t)slot * 384 + 256 + 2 * lane) = o2;
    }
}

// ---------------------------------------------------------------------------
// up_final: up-GEMM (K=384, bf16 A) + relu + per-block pooled column sums
// (device atomicAdd into gwacc) + last-done-block computes gates for all b.
// ---------------------------------------------------------------------------
__global__ __launch_bounds__(256) void up_final_k(const unsigned short* __restrict__ nbc,
                                                  const float* __restrict__ upW,
                                                  const float* __restrict__ upb,
                                                  const int* __restrict__ wcnt,
                                                  float* __restrict__ gwacc,
                                                  int* __restrict__ done,
                                                  const float* __restrict__ nh,
                                                  const float* __restrict__ wgW,
                                                  const float* __restrict__ wgb,
                                                  const float* __restrict__ fgW,
                                                  const float* __restrict__ fgb,
                                                  float* __restrict__ out) {
    __shared__ __align__(16) float lA[32][68];
    __shared__ __align__(16) float lW[32][132];
    __shared__ float colsum[128];
    __shared__ float gwl[1024];
    __shared__ float nhl[1024];
    __shared__ int lastFlag;
    const int bid = blockIdx.x, tid = threadIdx.x;
    const int m0 = bid * 64;
    const int b = m0 >> 10;
    const int cnt = wcnt[b];
    const int r0 = (tid & 15) * 4;
    const int h0 = (tid >> 4) * 8;

    if ((m0 & 1023) < cnt) {  // block-uniform
        float acc[4][8] = {};
        for (int k0 = 0; k0 < 384; k0 += 32) {
            __syncthreads();
            {
                const int r = tid >> 2, kk = (tid & 3) * 8;
                const unsigned short* src = nbc + (size_t)(m0 + r) * 384 + (k0 + kk);
                alignas(16) unsigned short us[8];
                *reinterpret_cast<uint4*>(us) = *reinterpret_cast<const uint4*>(src);
#pragma unroll
                for (int j = 0; j < 8; ++j) lA[kk + j][r] = bf2f(us[j]);
            }
            {
                const int kk = tid >> 3, hh = (tid & 7) * 16;
                const float* src = upW + (size_t)(k0 + kk) * 128 + hh;
#pragma unroll
                for (int q = 0; q < 4; ++q) {
                    float4 v = reinterpret_cast<const float4*>(src)[q];
                    lW[kk][hh + 4 * q + 0] = v.x; lW[kk][hh + 4 * q + 1] = v.y;
                    lW[kk][hh + 4 * q + 2] = v.z; lW[kk][hh + 4 * q + 3] = v.w;
                }
            }
            __syncthreads();
#pragma unroll
            for (int k = 0; k < 32; ++k) {
                float4 a  = *reinterpret_cast<const float4*>(&lA[k][r0]);
                float4 w0 = *reinterpret_cast<const float4*>(&lW[k][h0]);
                float4 w1 = *reinterpret_cast<const float4*>(&lW[k][h0 + 4]);
                float av[4] = {a.x, a.y, a.z, a.w};
                float wv[8] = {w0.x, w0.y, w0.z, w0.w, w1.x, w1.y, w1.z, w1.w};
#pragma unroll
                for (int i = 0; i < 4; ++i)
#pragma unroll
                    for (int j = 0; j < 8; ++j) acc[i][j] = fmaf(av[i], wv[j], acc[i][j]);
            }
        }
        if (tid < 128) colsum[tid] = 0.f;
        __syncthreads();
        float part[8] = {};
#pragma unroll
        for (int i = 0; i < 4; ++i) {
            const int m = m0 + r0 + i;
            if ((m & 1023) < cnt) {
#pragma unroll
                for (int j = 0; j < 8; ++j)
                    part[j] += fmaxf(acc[i][j] + upb[h0 + j], 0.f);
            }
        }
#pragma unroll
        for (int j = 0; j < 8; ++j) atomicAdd(&colsum[h0 + j], part[j]);
        __syncthreads();
        if (tid < 128) atomicAdd(&gwacc[b * 128 + tid], colsum[tid]);
    }
    __threadfence();
    if (tid == 0) {
        const int old = atomicAdd(done, 1);
        lastFlag = (old == (int)gridDim.x - 1);
    }
    __syncthreads();
    if (!lastFlag) return;
    __threadfence();
    // last block: stage gw (coherent atomic reads) + nh, compute gates
    for (int idx = tid; idx < 1024; idx += 256) {
        const int bb = idx >> 7;
        const float n = (float)wcnt[bb] + 1e-30f;
        gwl[idx] = atomicAdd(&gwacc[idx], 0.f) / n;
        nhl[idx] = nh[idx];
    }
    __syncthreads();
#pragma unroll
    for (int q = 0; q < 4; ++q) {
        const int o = q * 256 + tid;
        const int b2 = o >> 7, d = o & 127;
        const float* gwp = &gwl[b2 * 128];
        const float* nhp = &nhl[b2 * 128];
        float gu = wgb[d];
        for (int k = 0; k < 128; ++k) gu = fmaf(gwp[k], wgW[k * 128 + d], gu);
        gu = fmaxf(gu, 0.f);
        float fg = fgb[d];
        for (int k = 0; k < 128; ++k) fg = fmaf(gwp[k], fgW[k * 128 + d], fg);
        for (int k = 0; k < 128; ++k) fg = fmaf(nhp[k], fgW[(128 + k) * 128 + d], fg);
        const float forget = 1.f / (1.f + expf(-fg));
        out[o] = fmaxf(forget, 0.1f) * nhp[d] + (1.f - forget) * gu;
    }
}

// ---------------------------------------------------------------------------
extern "C" void kernel_launch(void* const* d_in, const int* in_sizes, int n_in,
                              void* d_out, int out_size, void* d_ws, size_t ws_size,
                              hipStream_t stream) {
    (void)in_sizes; (void)n_in; (void)out_size; (void)ws_size;
    const float* word_outputs        = (const float*)d_in[0];
    const float* node_hidden         = (const float*)d_in[1];
    const float* op_embedding        = (const float*)d_in[2];
    const float* word_operator       = (const float*)d_in[3];
    const float* word_word           = (const float*)d_in[4];
    const float* depend_relation     = (const float*)d_in[5];
    const float* word_exist_matrix   = (const float*)d_in[6];
    const float* word_exist_sequence = (const float*)d_in[7];
    const float* goal_word           = (const float*)d_in[8];
    const float* o_w_W = (const float*)d_in[9];
    const float* o_w_b = (const float*)d_in[10];
    const float* wk_W  = (const float*)d_in[11];
    const float* wk_b  = (const float*)d_in[12];
    const float* ws_W  = (const float*)d_in[13];
    const float* ws_b  = (const float*)d_in[14];
    const float* up_W  = (const float*)d_in[15];
    const float* up_b  = (const float*)d_in[16];
    const float* wg_W  = (const float*)d_in[17];
    const float* wg_b  = (const float*)d_in[18];
    const float* fg_W  = (const float*)d_in[19];
    const float* fg_b  = (const float*)d_in[20];
    float* out = (float*)d_out;

    char* ws = (char*)d_ws;
    unsigned short* oph = (unsigned short*)(ws + 0);           // 128 KB
    unsigned short* wkh = (unsigned short*)(ws + (1u << 20));  // 4 MB
    unsigned short* wsh = (unsigned short*)(ws + (5u << 20));  // 4 MB
    int* widx           = (int*)(ws + (9u << 20));             // 32 KB
    int* wcnt           = (int*)(ws + (9u << 20) + 32768);     // 32 B
    float* gwacc        = (float*)(ws + (9u << 20) + 65536);   // 4 KB
    int* done           = (int*)(ws + (9u << 20) + 131072);    // 4 B
    unsigned short* nbc = (unsigned short*)(ws + (10u << 20)); // 6 MB

    prep_k<<<273, 256, 0, stream>>>(word_outputs, wk_W, ws_W, wk_b, ws_b, wkh, wsh,
                                    op_embedding, o_w_W, o_w_b, oph,
                                    goal_word, word_exist_sequence, widx, wcnt,
                                    gwacc, done);
    mega_agg<<<8192, 256, 0, stream>>>(widx, wcnt, word_word, word_exist_matrix,
                                       depend_relation, word_operator, oph, wkh, wsh, nbc);
    up_final_k<<<128, 256, 0, stream>>>(nbc, up_W, up_b, wcnt, gwacc, done,
                                        node_hidden, wg_W, wg_b, fg_W, fg_b, out);
}

// Round 20
// 362.507 us; speedup vs baseline: 1.0706x; 1.0706x over previous
//
#include <hip/hip_runtime.h>
#include <math.h>

#define Sn 4
#define Bn 8
#define Ln 512
#define Dn 128
#define Hn 128
#define NOPn 64
#define Wn 2048

// ESTABLISHED: inputs fp32 insertion order; output fp32; bf16-space compare
// (thr 3.6e-2); ws = 512MB; harness tax ~170-200us/iter. R18 381us (6 kernels),
// R19 388us (3 kernels — last-block gate tail cost 70us on one CU, reverted).
// R20: prep fusion kept, tail split back to up_gemm_c + final3_k (4 kernels).

__device__ __forceinline__ float bf2f(unsigned short u) {
    return __uint_as_float(((unsigned int)u) << 16);
}
__device__ __forceinline__ unsigned short f2bf(float f) {
    unsigned int u = __float_as_uint(f);
    return (unsigned short)((u + 0x7FFFu + ((u >> 16) & 1u)) >> 16);  // RNE
}

// ---------------------------------------------------------------------------
// prep_k: blockIdx branches.
//   0..255   : dual GEMM tile (wkh/wsh from word_outputs)
//   256..263 : op-embedding GEMM tile (oph)
//   264..271 : compact pooled indices for b = bid-264
// ---------------------------------------------------------------------------
__global__ __launch_bounds__(256) void prep_k(const float* __restrict__ A,
                                              const float* __restrict__ W1,
                                              const float* __restrict__ W2,
                                              const float* __restrict__ b1,
                                              const float* __restrict__ b2,
                                              unsigned short* __restrict__ C1,
                                              unsigned short* __restrict__ C2,
                                              const float* __restrict__ ope,
                                              const float* __restrict__ owW,
                                              const float* __restrict__ owb,
                                              unsigned short* __restrict__ oph,
                                              const float* __restrict__ goal,
                                              const float* __restrict__ wes,
                                              int* __restrict__ widx,
                                              int* __restrict__ wcnt) {
    __shared__ __align__(16) float lA[32][68];
    __shared__ __align__(16) float lW1[32][132];
    __shared__ __align__(16) float lW2[32][132];
    __shared__ int cnt;
    const int bid = blockIdx.x, tid = threadIdx.x;

    if (bid < 256) {  // ---- dual GEMM ----
        const int m0 = bid * 64;
        float acc1[4][8] = {}, acc2[4][8] = {};
        const int r0 = (tid & 15) * 4;
        const int h0 = (tid >> 4) * 8;
        for (int k0 = 0; k0 < 128; k0 += 32) {
            __syncthreads();
            {
                const int r = tid >> 2, kk = (tid & 3) * 8;
                const float* src = A + (size_t)(m0 + r) * 128 + (k0 + kk);
                float4 v0 = reinterpret_cast<const float4*>(src)[0];
                float4 v1 = reinterpret_cast<const float4*>(src)[1];
                lA[kk + 0][r] = v0.x; lA[kk + 1][r] = v0.y;
                lA[kk + 2][r] = v0.z; lA[kk + 3][r] = v0.w;
                lA[kk + 4][r] = v1.x; lA[kk + 5][r] = v1.y;
                lA[kk + 6][r] = v1.z; lA[kk + 7][r] = v1.w;
            }
            {
                const int kk = tid >> 3, hh = (tid & 7) * 16;
                const float* s1 = W1 + (size_t)(k0 + kk) * 128 + hh;
                const float* s2 = W2 + (size_t)(k0 + kk) * 128 + hh;
#pragma unroll
                for (int q = 0; q < 4; ++q) {
                    float4 v1 = reinterpret_cast<const float4*>(s1)[q];
                    float4 v2 = reinterpret_cast<const float4*>(s2)[q];
                    lW1[kk][hh + 4 * q + 0] = v1.x; lW1[kk][hh + 4 * q + 1] = v1.y;
                    lW1[kk][hh + 4 * q + 2] = v1.z; lW1[kk][hh + 4 * q + 3] = v1.w;
                    lW2[kk][hh + 4 * q + 0] = v2.x; lW2[kk][hh + 4 * q + 1] = v2.y;
                    lW2[kk][hh + 4 * q + 2] = v2.z; lW2[kk][hh + 4 * q + 3] = v2.w;
                }
            }
            __syncthreads();
#pragma unroll
            for (int k = 0; k < 32; ++k) {
                float4 a   = *reinterpret_cast<const float4*>(&lA[k][r0]);
                float4 w10 = *reinterpret_cast<const float4*>(&lW1[k][h0]);
                float4 w11 = *reinterpret_cast<const float4*>(&lW1[k][h0 + 4]);
                float4 w20 = *reinterpret_cast<const float4*>(&lW2[k][h0]);
                float4 w21 = *reinterpret_cast<const float4*>(&lW2[k][h0 + 4]);
                float av[4] = {a.x, a.y, a.z, a.w};
                float wv1[8] = {w10.x, w10.y, w10.z, w10.w, w11.x, w11.y, w11.z, w11.w};
                float wv2[8] = {w20.x, w20.y, w20.z, w20.w, w21.x, w21.y, w21.z, w21.w};
#pragma unroll
                for (int i = 0; i < 4; ++i)
#pragma unroll
                    for (int j = 0; j < 8; ++j) {
                        acc1[i][j] = fmaf(av[i], wv1[j], acc1[i][j]);
                        acc2[i][j] = fmaf(av[i], wv2[j], acc2[i][j]);
                    }
            }
        }
#pragma unroll
        for (int i = 0; i < 4; ++i) {
            alignas(16) unsigned short u1[8], u2[8];
#pragma unroll
            for (int j = 0; j < 8; ++j) {
                u1[j] = f2bf(acc1[i][j] + b1[h0 + j]);
                u2[j] = f2bf(acc2[i][j] + b2[h0 + j]);
            }
            const size_t off = (size_t)(m0 + r0 + i) * 128 + h0;
            *reinterpret_cast<uint4*>(C1 + off) = *reinterpret_cast<const uint4*>(u1);
            *reinterpret_cast<uint4*>(C2 + off) = *reinterpret_cast<const uint4*>(u2);
        }
    } else if (bid < 264) {  // ---- oph GEMM ----
        const int m0 = (bid - 256) * 64;
        float acc[4][8] = {};
        const int r0 = (tid & 15) * 4;
        const int h0 = (tid >> 4) * 8;
        for (int k0 = 0; k0 < 128; k0 += 32) {
            __syncthreads();
            {
                const int r = tid >> 2, kk = (tid & 3) * 8;
                const float* src = ope + (size_t)(m0 + r) * 128 + (k0 + kk);
                float4 v0 = reinterpret_cast<const float4*>(src)[0];
                float4 v1 = reinterpret_cast<const float4*>(src)[1];
                lA[kk + 0][r] = v0.x; lA[kk + 1][r] = v0.y;
                lA[kk + 2][r] = v0.z; lA[kk + 3][r] = v0.w;
                lA[kk + 4][r] = v1.x; lA[kk + 5][r] = v1.y;
                lA[kk + 6][r] = v1.z; lA[kk + 7][r] = v1.w;
            }
            {
                const int kk = tid >> 3, hh = (tid & 7) * 16;
                const float* src = owW + (size_t)(k0 + kk) * 128 + hh;
#pragma unroll
                for (int q = 0; q < 4; ++q) {
                    float4 v = reinterpret_cast<const float4*>(src)[q];
                    lW1[kk][hh + 4 * q + 0] = v.x; lW1[kk][hh + 4 * q + 1] = v.y;
                    lW1[kk][hh + 4 * q + 2] = v.z; lW1[kk][hh + 4 * q + 3] = v.w;
                }
            }
            __syncthreads();
#pragma unroll
            for (int k = 0; k < 32; ++k) {
                float4 a  = *reinterpret_cast<const float4*>(&lA[k][r0]);
                float4 w0 = *reinterpret_cast<const float4*>(&lW1[k][h0]);
                float4 w1 = *reinterpret_cast<const float4*>(&lW1[k][h0 + 4]);
                float av[4] = {a.x, a.y, a.z, a.w};
                float wv[8] = {w0.x, w0.y, w0.z, w0.w, w1.x, w1.y, w1.z, w1.w};
#pragma unroll
                for (int i = 0; i < 4; ++i)
#pragma unroll
                    for (int j = 0; j < 8; ++j) acc[i][j] = fmaf(av[i], wv[j], acc[i][j]);
            }
        }
#pragma unroll
        for (int i = 0; i < 4; ++i) {
            alignas(16) unsigned short us[8];
#pragma unroll
            for (int j = 0; j < 8; ++j) us[j] = f2bf(acc[i][j] + owb[h0 + j]);
            *reinterpret_cast<uint4*>(oph + (size_t)(m0 + r0 + i) * 128 + h0) =
                *reinterpret_cast<const uint4*>(us);
        }
    } else {  // ---- compact ----
        const int b = bid - 264;
        if (tid == 0) cnt = 0;
        __syncthreads();
#pragma unroll
        for (int j = 0; j < 8; ++j) {
            const int w = tid * 8 + j;
            if (goal[b * Wn + w] != 0.f && wes[b * Wn + w] != 0.f) {
                const int p = atomicAdd(&cnt, 1);
                if (p < 1024) widx[b * 1024 + p] = w;
            }
        }
        __syncthreads();
        if (tid == 0) wcnt[b] = cnt < 1024 ? cnt : 1024;
    }
}

// ---------------------------------------------------------------------------
// mega_agg: ONE block (256 thr / 4 waves) per pooled destination row.
// ---------------------------------------------------------------------------
__global__ __launch_bounds__(256) void mega_agg(const int* __restrict__ widx,
                                                const int* __restrict__ wcnt,
                                                const float* __restrict__ ww,
                                                const float* __restrict__ wem,
                                                const float* __restrict__ dep,
                                                const float* __restrict__ wop,
                                                const unsigned short* __restrict__ oph,
                                                const unsigned short* __restrict__ wkh,
                                                const unsigned short* __restrict__ wsh,
                                                unsigned short* __restrict__ nbc) {
    const int slot = blockIdx.x;          // b*1024 + i
    const int b = slot >> 10, i = slot & 1023;
    if (i >= wcnt[b]) return;             // uniform exit
    const int w_dst = widx[slot];
    const int t = threadIdx.x;
    const int lane = t & 63, wv = t >> 6;

    __shared__ int kidx[512];
    __shared__ int keep[512];
    __shared__ int sidx[256];
    __shared__ int kn, sn;
    __shared__ float part1[4][128];
    __shared__ float part2[4][128];
    if (t == 0) { kn = 0; sn = 0; }
    __syncthreads();

    const float* wwr = ww + ((size_t)(b * Wn + w_dst)) * Wn;
#pragma unroll
    for (int q = 0; q < 2; ++q) {
        const int e0 = q * 1024 + t * 4;
        float4 v = *reinterpret_cast<const float4*>(wwr + e0);
        float vv[4] = {v.x, v.y, v.z, v.w};
#pragma unroll
        for (int j = 0; j < 4; ++j)
            if (vv[j] != 0.f) {
                int p = atomicAdd(&kn, 1);
                if (p < 512) kidx[p] = e0 + j;
            }
    }
    const int sD = w_dst >> 9, lD = w_dst & 511;
    if (t < 128) {
        const float* dr = dep + ((size_t)((sD * Bn + b) * Ln + lD)) * Ln + t * 4;
        float4 v = *reinterpret_cast<const float4*>(dr);
        float vv[4] = {v.x, v.y, v.z, v.w};
#pragma unroll
        for (int j = 0; j < 4; ++j)
            if (vv[j] != 0.f) {
                int p = atomicAdd(&sn, 1);
                if (p < 256) sidx[p] = t * 4 + j;
            }
    }
    float m_op = 0.f;
    if (wv == 3) m_op = wop[((size_t)(b * Wn + w_dst)) * NOPn + lane];
    __syncthreads();

    const int nk = kn < 512 ? kn : 512;
    const int ns = sn < 256 ? sn : 256;
    for (int p = t; p < nk; p += 256)
        keep[p] = (wem[((size_t)(b * Wn + w_dst)) * Wn + kidx[p]] != 0.f) ? 1 : 0;
    __syncthreads();

    {   // slot1 gather
        float a0 = 0.f, a1 = 0.f;
        for (int p = wv; p < nk; p += 4)
            if (keep[p]) {
                const int w = kidx[p];
                const int s = w >> 9, l = w & 511;
                ushort2 x = *reinterpret_cast<const ushort2*>(
                    wkh + ((size_t)((s * Bn + b) * Ln + l)) * Hn + 2 * lane);
                a0 += bf2f(x.x);
                a1 += bf2f(x.y);
            }
        part1[wv][2 * lane]     = a0;
        part1[wv][2 * lane + 1] = a1;
    }
    {   // slot2 gather
        const unsigned short* base = wsh + (size_t)((sD * Bn + b) * Ln) * Hn + 2 * lane;
        float a0 = 0.f, a1 = 0.f;
        for (int p = wv; p < ns; p += 4) {
            ushort2 x = *reinterpret_cast<const ushort2*>(base + (size_t)sidx[p] * Hn);
            a0 += bf2f(x.x);
            a1 += bf2f(x.y);
        }
        part2[wv][2 * lane]     = a0;
        part2[wv][2 * lane + 1] = a1;
    }
    if (wv == 3) {  // slot0
        unsigned long long bal = __ballot(m_op != 0.f);
        float a0 = 0.f, a1 = 0.f;
        const unsigned short* base = oph + (size_t)b * NOPn * Hn + 2 * lane;
        while (bal) {
            const int o = __ffsll(bal) - 1;
            bal &= bal - 1;
            ushort2 v = *reinterpret_cast<const ushort2*>(base + o * Hn);
            a0 += bf2f(v.x);
            a1 += bf2f(v.y);
        }
        float ss = a0 * a0 + a1 * a1;
#pragma unroll
        for (int off = 1; off < 64; off <<= 1) ss += __shfl_xor(ss, off);
        const float sc = 1.f / (sqrtf(ss) + 1e-30f);
        ushort2 o2 = {f2bf(a0 * sc), f2bf(a1 * sc)};
        *reinterpret_cast<ushort2*>(nbc + (size_t)slot * 384 + 2 * lane) = o2;
    }
    __syncthreads();

    if (wv == 0) {
        float s0 = 0.f, s1 = 0.f;
#pragma unroll
        for (int q = 0; q < 4; ++q) {
            s0 += part1[q][2 * lane];
            s1 += part1[q][2 * lane + 1];
        }
        float ss = s0 * s0 + s1 * s1;
#pragma unroll
        for (int off = 1; off < 64; off <<= 1) ss += __shfl_xor(ss, off);
        const float sc = 1.f / (sqrtf(ss) + 1e-30f);
        ushort2 o2 = {f2bf(s0 * sc), f2bf(s1 * sc)};
        *reinterpret_cast<ushort2*>(nbc + (size_t)slot * 384 + 128 + 2 * lane) = o2;
    } else if (wv == 1) {
        float s0 = 0.f, s1 = 0.f;
#pragma unroll
        for (int q = 0; q < 4; ++q) {
            s0 += part2[q][2 * lane];
            s1 += part2[q][2 * lane + 1];
        }
        float ss = s0 * s0 + s1 * s1;
#pragma unroll
        for (int off = 1; off < 64; off <<= 1) ss += __shfl_xor(ss, off);
        const float sc = 1.f / (sqrtf(ss) + 1e-30f);
        ushort2 o2 = {f2bf(s0 * sc), f2bf(s1 * sc)};
        *reinterpret_cast<ushort2*>(nbc + (size_t)slot * 384 + 256 + 2 * lane) = o2;
    }
}

// ---------------------------------------------------------------------------
// up-GEMM over compacted rows (K=384, bf16 A, relu, fp32 out, cnt guard).
// ---------------------------------------------------------------------------
__global__ __launch_bounds__(256) void up_gemm_c(const unsigned short* __restrict__ A,
                                                 const float* __restrict__ Wm,
                                                 const float* __restrict__ bias,
                                                 const int* __restrict__ wcnt,
                                                 float* __restrict__ C) {
    const int m0 = blockIdx.x * 64;
    if ((m0 & 1023) >= wcnt[m0 >> 10]) return;  // whole 64-row tile unused
    __shared__ __align__(16) float lA[32][68];
    __shared__ __align__(16) float lW[32][132];
    const int tid = threadIdx.x;
    float acc[4][8] = {};
    const int r0 = (tid & 15) * 4;
    const int h0 = (tid >> 4) * 8;
    for (int k0 = 0; k0 < 384; k0 += 32) {
        __syncthreads();
        {
            const int r = tid >> 2, kk = (tid & 3) * 8;
            const unsigned short* src = A + (size_t)(m0 + r) * 384 + (k0 + kk);
            alignas(16) unsigned short us[8];
            *reinterpret_cast<uint4*>(us) = *reinterpret_cast<const uint4*>(src);
#pragma unroll
            for (int j = 0; j < 8; ++j) lA[kk + j][r] = bf2f(us[j]);
        }
        {
            const int kk = tid >> 3, hh = (tid & 7) * 16;
            const float* src = Wm + (size_t)(k0 + kk) * 128 + hh;
#pragma unroll
            for (int q = 0; q < 4; ++q) {
                float4 v = reinterpret_cast<const float4*>(src)[q];
                lW[kk][hh + 4 * q + 0] = v.x; lW[kk][hh + 4 * q + 1] = v.y;
                lW[kk][hh + 4 * q + 2] = v.z; lW[kk][hh + 4 * q + 3] = v.w;
            }
        }
        __syncthreads();
#pragma unroll
        for (int k = 0; k < 32; ++k) {
            float4 a  = *reinterpret_cast<const float4*>(&lA[k][r0]);
            float4 w0 = *reinterpret_cast<const float4*>(&lW[k][h0]);
            float4 w1 = *reinterpret_cast<const float4*>(&lW[k][h0 + 4]);
            float av[4] = {a.x, a.y, a.z, a.w};
            float wv[8] = {w0.x, w0.y, w0.z, w0.w, w1.x, w1.y, w1.z, w1.w};
#pragma unroll
            for (int i = 0; i < 4; ++i)
#pragma unroll
                for (int j = 0; j < 8; ++j) acc[i][j] = fmaf(av[i], wv[j], acc[i][j]);
        }
    }
#pragma unroll
    for (int i = 0; i < 4; ++i) {
        float o[8];
#pragma unroll
        for (int j = 0; j < 8; ++j) o[j] = fmaxf(acc[i][j] + bias[h0 + j], 0.f);
        float* dst = C + (size_t)(m0 + r0 + i) * 128 + h0;
        *reinterpret_cast<float4*>(dst)     = reinterpret_cast<float4&>(o[0]);
        *reinterpret_cast<float4*>(dst + 4) = reinterpret_cast<float4&>(o[4]);
    }
}

// ---------------------------------------------------------------------------
// final3: pool compacted wu rows (mean over n), two GEMVs, gates.
// ---------------------------------------------------------------------------
__global__ __launch_bounds__(1024) void final3_k(const int* __restrict__ wcnt,
                                                 const float* __restrict__ wuc,
                                                 const float* __restrict__ nh,
                                                 const float* __restrict__ wgW,
                                                 const float* __restrict__ wgb,
                                                 const float* __restrict__ fgW,
                                                 const float* __restrict__ fgb,
                                                 float* __restrict__ out) {
    const int b = blockIdx.x, t = threadIdx.x;
    const int d = t & 127, sl = t >> 7;
    __shared__ float red[1024];
    __shared__ float gw[Dn], nhs[Dn];
    const int n = wcnt[b];
    float acc = 0.f;
    for (int p = sl; p < n; p += 8) acc += wuc[((size_t)(b * 1024 + p)) * Dn + d];
    red[t] = acc;
    __syncthreads();
    for (int s = 512; s >= 128; s >>= 1) {
        if (t < s) red[t] += red[t + s];
        __syncthreads();
    }
    if (t < 128) {
        gw[t] = red[t] / ((float)n + 1e-30f);
        nhs[t] = nh[b * Dn + t];
    }
    __syncthreads();
    float pg = 0.f;
    for (int k = sl * 16; k < sl * 16 + 16; ++k) pg = fmaf(gw[k], wgW[k * Dn + d], pg);
    red[t] = pg;
    __syncthreads();
    for (int s = 512; s >= 128; s >>= 1) {
        if (t < s) red[t] += red[t + s];
        __syncthreads();
    }
    float gu = 0.f;
    if (t < 128) gu = fmaxf(red[t] + wgb[t], 0.f);
    __syncthreads();
    float pf = 0.f;
    for (int kk = sl * 32; kk < sl * 32 + 32; ++kk) {
        const float x = (kk < 128) ? gw[kk] : nhs[kk - 128];
        pf = fmaf(x, fgW[(size_t)kk * Dn + d], pf);
    }
    red[t] = pf;
    __syncthreads();
    for (int s = 512; s >= 128; s >>= 1) {
        if (t < s) red[t] += red[t + s];
        __syncthreads();
    }
    if (t < 128) {
        const float fg = red[t] + fgb[t];
        const float forget = 1.f / (1.f + expf(-fg));
        out[b * Dn + t] = fmaxf(forget, 0.1f) * nhs[t] + (1.f - forget) * gu;
    }
}

// ---------------------------------------------------------------------------
extern "C" void kernel_launch(void* const* d_in, const int* in_sizes, int n_in,
                              void* d_out, int out_size, void* d_ws, size_t ws_size,
                              hipStream_t stream) {
    (void)in_sizes; (void)n_in; (void)out_size; (void)ws_size;
    const float* word_outputs        = (const float*)d_in[0];
    const float* node_hidden         = (const float*)d_in[1];
    const float* op_embedding        = (const float*)d_in[2];
    const float* word_operator       = (const float*)d_in[3];
    const float* word_word           = (const float*)d_in[4];
    const float* depend_relation     = (const float*)d_in[5];
    const float* word_exist_matrix   = (const float*)d_in[6];
    const float* word_exist_sequence = (const float*)d_in[7];
    const float* goal_word           = (const float*)d_in[8];
    const float* o_w_W = (const float*)d_in[9];
    const float* o_w_b = (const float*)d_in[10];
    const float* wk_W  = (const float*)d_in[11];
    const float* wk_b  = (const float*)d_in[12];
    const float* ws_W  = (const float*)d_in[13];
    const float* ws_b  = (const float*)d_in[14];
    const float* up_W  = (const float*)d_in[15];
    const float* up_b  = (const float*)d_in[16];
    const float* wg_W  = (const float*)d_in[17];
    const float* wg_b  = (const float*)d_in[18];
    const float* fg_W  = (const float*)d_in[19];
    const float* fg_b  = (const float*)d_in[20];
    float* out = (float*)d_out;

    char* ws = (char*)d_ws;
    unsigned short* oph = (unsigned short*)(ws + 0);           // 128 KB
    unsigned short* wkh = (unsigned short*)(ws + (1u << 20));  // 4 MB
    unsigned short* wsh = (unsigned short*)(ws + (5u << 20));  // 4 MB
    int* widx           = (int*)(ws + (9u << 20));             // 32 KB
    int* wcnt           = (int*)(ws + (9u << 20) + 32768);     // 32 B
    unsigned short* nbc = (unsigned short*)(ws + (10u << 20)); // 6 MB
    float* wuc          = (float*)(ws + (17u << 20));          // 4 MB

    prep_k<<<272, 256, 0, stream>>>(word_outputs, wk_W, ws_W, wk_b, ws_b, wkh, wsh,
                                    op_embedding, o_w_W, o_w_b, oph,
                                    goal_word, word_exist_sequence, widx, wcnt);
    mega_agg<<<8192, 256, 0, stream>>>(widx, wcnt, word_word, word_exist_matrix,
                                       depend_relation, word_operator, oph, wkh, wsh, nbc);
    up_gemm_c<<<128, 256, 0, stream>>>(nbc, up_W, up_b, wcnt, wuc);
    final3_k<<<8, 1024, 0, stream>>>(wcnt, wuc, node_hidden,
                                     wg_W, wg_b, fg_W, fg_b, out);
}

// Round 21
// 355.085 us; speedup vs baseline: 1.0930x; 1.0209x over previous
//
#include <hip/hip_runtime.h>
#include <math.h>

#define Sn 4
#define Bn 8
#define Ln 512
#define Dn 128
#define Hn 128
#define NOPn 64
#define Wn 2048

// ESTABLISHED: inputs fp32 insertion order; output fp32; bf16-space compare
// (thr 3.6e-2); ws = 512MB; harness tax ~220-260us/iter (restore+poison+gaps,
// ~10us per dispatch). R20 362us (4 kernels). R21: fuse up-GEMV into
// mega_agg (per-row GEMV + atomic pooled sum), 3 kernels, no nbc/wuc.

__device__ __forceinline__ float bf2f(unsigned short u) {
    return __uint_as_float(((unsigned int)u) << 16);
}
__device__ __forceinline__ unsigned short f2bf(float f) {
    unsigned int u = __float_as_uint(f);
    return (unsigned short)((u + 0x7FFFu + ((u >> 16) & 1u)) >> 16);  // RNE
}

// ---------------------------------------------------------------------------
// prep_k: blockIdx branches.
//   0..255   : dual GEMM tile (wkh/wsh from word_outputs)
//   256..263 : op-embedding GEMM tile (oph)
//   264..271 : compact pooled indices for b = bid-264
//   272      : zero gwacc
// ---------------------------------------------------------------------------
__global__ __launch_bounds__(256) void prep_k(const float* __restrict__ A,
                                              const float* __restrict__ W1,
                                              const float* __restrict__ W2,
                                              const float* __restrict__ b1,
                                              const float* __restrict__ b2,
                                              unsigned short* __restrict__ C1,
                                              unsigned short* __restrict__ C2,
                                              const float* __restrict__ ope,
                                              const float* __restrict__ owW,
                                              const float* __restrict__ owb,
                                              unsigned short* __restrict__ oph,
                                              const float* __restrict__ goal,
                                              const float* __restrict__ wes,
                                              int* __restrict__ widx,
                                              int* __restrict__ wcnt,
                                              float* __restrict__ gwacc) {
    __shared__ __align__(16) float lA[32][68];
    __shared__ __align__(16) float lW1[32][132];
    __shared__ __align__(16) float lW2[32][132];
    __shared__ int cnt;
    const int bid = blockIdx.x, tid = threadIdx.x;

    if (bid < 256) {  // ---- dual GEMM ----
        const int m0 = bid * 64;
        float acc1[4][8] = {}, acc2[4][8] = {};
        const int r0 = (tid & 15) * 4;
        const int h0 = (tid >> 4) * 8;
        for (int k0 = 0; k0 < 128; k0 += 32) {
            __syncthreads();
            {
                const int r = tid >> 2, kk = (tid & 3) * 8;
                const float* src = A + (size_t)(m0 + r) * 128 + (k0 + kk);
                float4 v0 = reinterpret_cast<const float4*>(src)[0];
                float4 v1 = reinterpret_cast<const float4*>(src)[1];
                lA[kk + 0][r] = v0.x; lA[kk + 1][r] = v0.y;
                lA[kk + 2][r] = v0.z; lA[kk + 3][r] = v0.w;
                lA[kk + 4][r] = v1.x; lA[kk + 5][r] = v1.y;
                lA[kk + 6][r] = v1.z; lA[kk + 7][r] = v1.w;
            }
            {
                const int kk = tid >> 3, hh = (tid & 7) * 16;
                const float* s1 = W1 + (size_t)(k0 + kk) * 128 + hh;
                const float* s2 = W2 + (size_t)(k0 + kk) * 128 + hh;
#pragma unroll
                for (int q = 0; q < 4; ++q) {
                    float4 v1 = reinterpret_cast<const float4*>(s1)[q];
                    float4 v2 = reinterpret_cast<const float4*>(s2)[q];
                    lW1[kk][hh + 4 * q + 0] = v1.x; lW1[kk][hh + 4 * q + 1] = v1.y;
                    lW1[kk][hh + 4 * q + 2] = v1.z; lW1[kk][hh + 4 * q + 3] = v1.w;
                    lW2[kk][hh + 4 * q + 0] = v2.x; lW2[kk][hh + 4 * q + 1] = v2.y;
                    lW2[kk][hh + 4 * q + 2] = v2.z; lW2[kk][hh + 4 * q + 3] = v2.w;
                }
            }
            __syncthreads();
#pragma unroll
            for (int k = 0; k < 32; ++k) {
                float4 a   = *reinterpret_cast<const float4*>(&lA[k][r0]);
                float4 w10 = *reinterpret_cast<const float4*>(&lW1[k][h0]);
                float4 w11 = *reinterpret_cast<const float4*>(&lW1[k][h0 + 4]);
                float4 w20 = *reinterpret_cast<const float4*>(&lW2[k][h0]);
                float4 w21 = *reinterpret_cast<const float4*>(&lW2[k][h0 + 4]);
                float av[4] = {a.x, a.y, a.z, a.w};
                float wv1[8] = {w10.x, w10.y, w10.z, w10.w, w11.x, w11.y, w11.z, w11.w};
                float wv2[8] = {w20.x, w20.y, w20.z, w20.w, w21.x, w21.y, w21.z, w21.w};
#pragma unroll
                for (int i = 0; i < 4; ++i)
#pragma unroll
                    for (int j = 0; j < 8; ++j) {
                        acc1[i][j] = fmaf(av[i], wv1[j], acc1[i][j]);
                        acc2[i][j] = fmaf(av[i], wv2[j], acc2[i][j]);
                    }
            }
        }
#pragma unroll
        for (int i = 0; i < 4; ++i) {
            alignas(16) unsigned short u1[8], u2[8];
#pragma unroll
            for (int j = 0; j < 8; ++j) {
                u1[j] = f2bf(acc1[i][j] + b1[h0 + j]);
                u2[j] = f2bf(acc2[i][j] + b2[h0 + j]);
            }
            const size_t off = (size_t)(m0 + r0 + i) * 128 + h0;
            *reinterpret_cast<uint4*>(C1 + off) = *reinterpret_cast<const uint4*>(u1);
            *reinterpret_cast<uint4*>(C2 + off) = *reinterpret_cast<const uint4*>(u2);
        }
    } else if (bid < 264) {  // ---- oph GEMM ----
        const int m0 = (bid - 256) * 64;
        float acc[4][8] = {};
        const int r0 = (tid & 15) * 4;
        const int h0 = (tid >> 4) * 8;
        for (int k0 = 0; k0 < 128; k0 += 32) {
            __syncthreads();
            {
                const int r = tid >> 2, kk = (tid & 3) * 8;
                const float* src = ope + (size_t)(m0 + r) * 128 + (k0 + kk);
                float4 v0 = reinterpret_cast<const float4*>(src)[0];
                float4 v1 = reinterpret_cast<const float4*>(src)[1];
                lA[kk + 0][r] = v0.x; lA[kk + 1][r] = v0.y;
                lA[kk + 2][r] = v0.z; lA[kk + 3][r] = v0.w;
                lA[kk + 4][r] = v1.x; lA[kk + 5][r] = v1.y;
                lA[kk + 6][r] = v1.z; lA[kk + 7][r] = v1.w;
            }
            {
                const int kk = tid >> 3, hh = (tid & 7) * 16;
                const float* src = owW + (size_t)(k0 + kk) * 128 + hh;
#pragma unroll
                for (int q = 0; q < 4; ++q) {
                    float4 v = reinterpret_cast<const float4*>(src)[q];
                    lW1[kk][hh + 4 * q + 0] = v.x; lW1[kk][hh + 4 * q + 1] = v.y;
                    lW1[kk][hh + 4 * q + 2] = v.z; lW1[kk][hh + 4 * q + 3] = v.w;
                }
            }
            __syncthreads();
#pragma unroll
            for (int k = 0; k < 32; ++k) {
                float4 a  = *reinterpret_cast<const float4*>(&lA[k][r0]);
                float4 w0 = *reinterpret_cast<const float4*>(&lW1[k][h0]);
                float4 w1 = *reinterpret_cast<const float4*>(&lW1[k][h0 + 4]);
                float av[4] = {a.x, a.y, a.z, a.w};
                float wv[8] = {w0.x, w0.y, w0.z, w0.w, w1.x, w1.y, w1.z, w1.w};
#pragma unroll
                for (int i = 0; i < 4; ++i)
#pragma unroll
                    for (int j = 0; j < 8; ++j) acc[i][j] = fmaf(av[i], wv[j], acc[i][j]);
            }
        }
#pragma unroll
        for (int i = 0; i < 4; ++i) {
            alignas(16) unsigned short us[8];
#pragma unroll
            for (int j = 0; j < 8; ++j) us[j] = f2bf(acc[i][j] + owb[h0 + j]);
            *reinterpret_cast<uint4*>(oph + (size_t)(m0 + r0 + i) * 128 + h0) =
                *reinterpret_cast<const uint4*>(us);
        }
    } else if (bid < 272) {  // ---- compact ----
        const int b = bid - 264;
        if (tid == 0) cnt = 0;
        __syncthreads();
#pragma unroll
        for (int j = 0; j < 8; ++j) {
            const int w = tid * 8 + j;
            if (goal[b * Wn + w] != 0.f && wes[b * Wn + w] != 0.f) {
                const int p = atomicAdd(&cnt, 1);
                if (p < 1024) widx[b * 1024 + p] = w;
            }
        }
        __syncthreads();
        if (tid == 0) wcnt[b] = cnt < 1024 ? cnt : 1024;
    } else {  // ---- zero gwacc ----
        for (int idx = tid; idx < 1024; idx += 256) gwacc[idx] = 0.f;
    }
}

// ---------------------------------------------------------------------------
// mega_agg2: ONE block per pooled destination row. Computes all 3 neighbor
// slots into LDS (fp32), then per-row up-GEMV g = relu(nb@upW+upb) and
// atomicAdd into gwacc[b*128+d]. No nbc/wuc round-trips.
// ---------------------------------------------------------------------------
__global__ __launch_bounds__(256) void mega_agg2(const int* __restrict__ widx,
                                                 const int* __restrict__ wcnt,
                                                 const float* __restrict__ ww,
                                                 const float* __restrict__ wem,
                                                 const float* __restrict__ dep,
                                                 const float* __restrict__ wop,
                                                 const unsigned short* __restrict__ oph,
                                                 const unsigned short* __restrict__ wkh,
                                                 const unsigned short* __restrict__ wsh,
                                                 const float* __restrict__ upW,
                                                 const float* __restrict__ upb,
                                                 float* __restrict__ gwacc) {
    const int slot = blockIdx.x;          // b*1024 + i
    const int b = slot >> 10, i = slot & 1023;
    if (i >= wcnt[b]) return;             // uniform exit
    const int w_dst = widx[slot];
    const int t = threadIdx.x;
    const int lane = t & 63, wv = t >> 6;

    __shared__ int kidx[512];
    __shared__ int keep[512];
    __shared__ int sidx[256];
    __shared__ int kn, sn;
    __shared__ float part1[4][128];
    __shared__ float part2[4][128];
    __shared__ float nbL[384];
    __shared__ float gpart[256];
    if (t == 0) { kn = 0; sn = 0; }
    __syncthreads();

    // --- p1: streams ---
    const float* wwr = ww + ((size_t)(b * Wn + w_dst)) * Wn;
#pragma unroll
    for (int q = 0; q < 2; ++q) {
        const int e0 = q * 1024 + t * 4;
        float4 v = *reinterpret_cast<const float4*>(wwr + e0);
        float vv[4] = {v.x, v.y, v.z, v.w};
#pragma unroll
        for (int j = 0; j < 4; ++j)
            if (vv[j] != 0.f) {
                int p = atomicAdd(&kn, 1);
                if (p < 512) kidx[p] = e0 + j;
            }
    }
    const int sD = w_dst >> 9, lD = w_dst & 511;
    if (t < 128) {
        const float* dr = dep + ((size_t)((sD * Bn + b) * Ln + lD)) * Ln + t * 4;
        float4 v = *reinterpret_cast<const float4*>(dr);
        float vv[4] = {v.x, v.y, v.z, v.w};
#pragma unroll
        for (int j = 0; j < 4; ++j)
            if (vv[j] != 0.f) {
                int p = atomicAdd(&sn, 1);
                if (p < 256) sidx[p] = t * 4 + j;
            }
    }
    float m_op = 0.f;
    if (wv == 3) m_op = wop[((size_t)(b * Wn + w_dst)) * NOPn + lane];
    __syncthreads();

    const int nk = kn < 512 ? kn : 512;
    const int ns = sn < 256 ? sn : 256;
    for (int p = t; p < nk; p += 256)
        keep[p] = (wem[((size_t)(b * Wn + w_dst)) * Wn + kidx[p]] != 0.f) ? 1 : 0;
    __syncthreads();

    // --- p3: gathers ---
    {   // slot1
        float a0 = 0.f, a1 = 0.f;
        for (int p = wv; p < nk; p += 4)
            if (keep[p]) {
                const int w = kidx[p];
                const int s = w >> 9, l = w & 511;
                ushort2 x = *reinterpret_cast<const ushort2*>(
                    wkh + ((size_t)((s * Bn + b) * Ln + l)) * Hn + 2 * lane);
                a0 += bf2f(x.x);
                a1 += bf2f(x.y);
            }
        part1[wv][2 * lane]     = a0;
        part1[wv][2 * lane + 1] = a1;
    }
    {   // slot2
        const unsigned short* base = wsh + (size_t)((sD * Bn + b) * Ln) * Hn + 2 * lane;
        float a0 = 0.f, a1 = 0.f;
        for (int p = wv; p < ns; p += 4) {
            ushort2 x = *reinterpret_cast<const ushort2*>(base + (size_t)sidx[p] * Hn);
            a0 += bf2f(x.x);
            a1 += bf2f(x.y);
        }
        part2[wv][2 * lane]     = a0;
        part2[wv][2 * lane + 1] = a1;
    }
    if (wv == 3) {  // slot0 -> nbL[0:128]
        unsigned long long bal = __ballot(m_op != 0.f);
        float a0 = 0.f, a1 = 0.f;
        const unsigned short* base = oph + (size_t)b * NOPn * Hn + 2 * lane;
        while (bal) {
            const int o = __ffsll(bal) - 1;
            bal &= bal - 1;
            ushort2 v = *reinterpret_cast<const ushort2*>(base + o * Hn);
            a0 += bf2f(v.x);
            a1 += bf2f(v.y);
        }
        float ss = a0 * a0 + a1 * a1;
#pragma unroll
        for (int off = 1; off < 64; off <<= 1) ss += __shfl_xor(ss, off);
        const float sc = 1.f / (sqrtf(ss) + 1e-30f);
        nbL[2 * lane]     = a0 * sc;
        nbL[2 * lane + 1] = a1 * sc;
    }
    __syncthreads();

    // --- p4: reduce+normalize slot1 (wave0) and slot2 (wave1) into nbL ---
    if (wv == 0) {
        float s0 = 0.f, s1 = 0.f;
#pragma unroll
        for (int q = 0; q < 4; ++q) {
            s0 += part1[q][2 * lane];
            s1 += part1[q][2 * lane + 1];
        }
        float ss = s0 * s0 + s1 * s1;
#pragma unroll
        for (int off = 1; off < 64; off <<= 1) ss += __shfl_xor(ss, off);
        const float sc = 1.f / (sqrtf(ss) + 1e-30f);
        nbL[128 + 2 * lane]     = s0 * sc;
        nbL[128 + 2 * lane + 1] = s1 * sc;
    } else if (wv == 1) {
        float s0 = 0.f, s1 = 0.f;
#pragma unroll
        for (int q = 0; q < 4; ++q) {
            s0 += part2[q][2 * lane];
            s1 += part2[q][2 * lane + 1];
        }
        float ss = s0 * s0 + s1 * s1;
#pragma unroll
        for (int off = 1; off < 64; off <<= 1) ss += __shfl_xor(ss, off);
        const float sc = 1.f / (sqrtf(ss) + 1e-30f);
        nbL[256 + 2 * lane]     = s0 * sc;
        nbL[256 + 2 * lane + 1] = s1 * sc;
    }
    __syncthreads();

    // --- p5: up-GEMV g[d] = relu(sum_k nbL[k]*upW[k,d] + upb[d]); pool ---
    {
        const int d = t & 127, half = t >> 7;
        float acc = 0.f;
        const float* wp = upW + (size_t)(half * 192) * 128 + d;
#pragma unroll 8
        for (int k = 0; k < 192; ++k)
            acc = fmaf(nbL[half * 192 + k], wp[(size_t)k * 128], acc);
        gpart[t] = acc;
    }
    __syncthreads();
    if (t < 128) {
        const float g = fmaxf(gpart[t] + gpart[t + 128] + upb[t], 0.f);
        atomicAdd(&gwacc[b * 128 + t], g);
    }
}

// ---------------------------------------------------------------------------
// final4: read pooled sums, mean, two GEMVs, gates. 8 blocks x 128 thr.
// ---------------------------------------------------------------------------
__global__ __launch_bounds__(128) void final4_k(const int* __restrict__ wcnt,
                                                const float* __restrict__ gwacc,
                                                const float* __restrict__ nh,
                                                const float* __restrict__ wgW,
                                                const float* __restrict__ wgb,
                                                const float* __restrict__ fgW,
                                                const float* __restrict__ fgb,
                                                float* __restrict__ out) {
    const int b = blockIdx.x, t = threadIdx.x;
    __shared__ float gw[Dn], nhs[Dn];
    const float inv = 1.f / ((float)wcnt[b] + 1e-30f);
    gw[t]  = gwacc[b * Dn + t] * inv;
    nhs[t] = nh[b * Dn + t];
    __syncthreads();
    float gu = wgb[t];
    for (int d = 0; d < Dn; ++d) gu = fmaf(gw[d], wgW[d * Dn + t], gu);
    gu = fmaxf(gu, 0.f);
    float fg = fgb[t];
    for (int d = 0; d < Dn; ++d) fg = fmaf(gw[d], fgW[d * Dn + t], fg);
    for (int d = 0; d < Dn; ++d) fg = fmaf(nhs[d], fgW[(Dn + d) * Dn + t], fg);
    const float forget = 1.f / (1.f + expf(-fg));
    out[b * Dn + t] = fmaxf(forget, 0.1f) * nhs[t] + (1.f - forget) * gu;
}

// ---------------------------------------------------------------------------
extern "C" void kernel_launch(void* const* d_in, const int* in_sizes, int n_in,
                              void* d_out, int out_size, void* d_ws, size_t ws_size,
                              hipStream_t stream) {
    (void)in_sizes; (void)n_in; (void)out_size; (void)ws_size;
    const float* word_outputs        = (const float*)d_in[0];
    const float* node_hidden         = (const float*)d_in[1];
    const float* op_embedding        = (const float*)d_in[2];
    const float* word_operator       = (const float*)d_in[3];
    const float* word_word           = (const float*)d_in[4];
    const float* depend_relation     = (const float*)d_in[5];
    const float* word_exist_matrix   = (const float*)d_in[6];
    const float* word_exist_sequence = (const float*)d_in[7];
    const float* goal_word           = (const float*)d_in[8];
    const float* o_w_W = (const float*)d_in[9];
    const float* o_w_b = (const float*)d_in[10];
    const float* wk_W  = (const float*)d_in[11];
    const float* wk_b  = (const float*)d_in[12];
    const float* ws_W  = (const float*)d_in[13];
    const float* ws_b  = (const float*)d_in[14];
    const float* up_W  = (const float*)d_in[15];
    const float* up_b  = (const float*)d_in[16];
    const float* wg_W  = (const float*)d_in[17];
    const float* wg_b  = (const float*)d_in[18];
    const float* fg_W  = (const float*)d_in[19];
    const float* fg_b  = (const float*)d_in[20];
    float* out = (float*)d_out;

    char* ws = (char*)d_ws;
    unsigned short* oph = (unsigned short*)(ws + 0);           // 128 KB
    unsigned short* wkh = (unsigned short*)(ws + (1u << 20));  // 4 MB
    unsigned short* wsh = (unsigned short*)(ws + (5u << 20));  // 4 MB
    int* widx           = (int*)(ws + (9u << 20));             // 32 KB
    int* wcnt           = (int*)(ws + (9u << 20) + 32768);     // 32 B
    float* gwacc        = (float*)(ws + (9u << 20) + 65536);   // 4 KB

    prep_k<<<273, 256, 0, stream>>>(word_outputs, wk_W, ws_W, wk_b, ws_b, wkh, wsh,
                                    op_embedding, o_w_W, o_w_b, oph,
                                    goal_word, word_exist_sequence, widx, wcnt, gwacc);
    mega_agg2<<<8192, 256, 0, stream>>>(widx, wcnt, word_word, word_exist_matrix,
                                        depend_relation, word_operator, oph, wkh, wsh,
                                        up_W, up_b, gwacc);
    final4_k<<<8, 128, 0, stream>>>(wcnt, gwacc, node_hidden,
                                    wg_W, wg_b, fg_W, fg_b, out);
}